// Round 1
// 563.488 us; speedup vs baseline: 1.4614x; 1.4614x over previous
//
#include <hip/hip_runtime.h>
#include <hip/hip_bf16.h>
#include <math.h>

// Problem constants (fixed by the reference setup_inputs)
#define BB 32
#define PP 24564
#define OO 16
#define CC 81
#define BP (BB * PP)
#define CHUNK 1024   // priors per k_match_a block; ceil(PP/CHUNK)=24 chunks

typedef unsigned long long ull;

__device__ __forceinline__ float sl1(float x) {
    float ax = fabsf(x);
    return ax < 1.0f ? 0.5f * ax * ax : ax - 0.5f;
}

// ---------------------------------------------------------------------------
// K1a: matching, parallel over (chunk, batch). Computes per-prior best-truth
// (bto/bti) and per-truth best-prior via packed-key atomicMax:
//   key = (iou_bits << 32) | (0xFFFFFFFF - p)   -> max iou, tie: smallest p
// ---------------------------------------------------------------------------
__global__ __launch_bounds__(256) void k_match_a(
        const float* __restrict__ priors, const float* __restrict__ truths,
        float* __restrict__ bto, int* __restrict__ bti,
        ull* __restrict__ best_prior /* [BB][OO], pre-zeroed */) {
    const int b = blockIdx.y;
    const int p0 = blockIdx.x * CHUNK;
    const int tid = threadIdx.x;
    __shared__ float tr[OO][4];
    __shared__ float tarea[OO];
    __shared__ ull red[OO];
    if (tid < OO * 4) ((float*)tr)[tid] = truths[b * OO * 4 + tid];
    if (tid < OO) red[tid] = 0ull;
    __syncthreads();
    if (tid < OO) tarea[tid] = (tr[tid][2] - tr[tid][0]) * (tr[tid][3] - tr[tid][1]);
    __syncthreads();

    float bpv[OO];
    int bpi[OO];
#pragma unroll
    for (int o = 0; o < OO; o++) { bpv[o] = -1.0f; bpi[o] = -1; }

    const int pend = (p0 + CHUNK < PP) ? p0 + CHUNK : PP;
    for (int p = p0 + tid; p < pend; p += 256) {
        const float4 pr = ((const float4*)priors)[p];
        const float x1 = pr.x - pr.z * 0.5f, y1 = pr.y - pr.w * 0.5f;
        const float x2 = pr.x + pr.z * 0.5f, y2 = pr.y + pr.w * 0.5f;
        const float parea = (x2 - x1) * (y2 - y1);
        float best = -1.0f;
        int bidx = 0;
#pragma unroll
        for (int o = 0; o < OO; o++) {
            const float lx = fmaxf(tr[o][0], x1), ly = fmaxf(tr[o][1], y1);
            const float rx = fminf(tr[o][2], x2), ry = fminf(tr[o][3], y2);
            const float iw = fmaxf(rx - lx, 0.0f), ih = fmaxf(ry - ly, 0.0f);
            const float inter = iw * ih;
            const float iou = inter / (tarea[o] + parea - inter);
            if (iou > best) { best = iou; bidx = o; }          // first-max over o
            if (iou > bpv[o]) { bpv[o] = iou; bpi[o] = p; }    // p ascending per thread
        }
        bto[(size_t)b * PP + p] = best;
        bti[(size_t)b * PP + p] = bidx;
    }

#pragma unroll
    for (int o = 0; o < OO; o++) {
        if (bpi[o] >= 0) {
            const ull key = ((ull)__float_as_uint(bpv[o]) << 32) |
                            (ull)(0xFFFFFFFFu - (unsigned)bpi[o]);
            atomicMax(&red[o], key);
        }
    }
    __syncthreads();
    if (tid < OO && red[tid] != 0ull)
        atomicMax(&best_prior[b * OO + tid], red[tid]);
}

// K1b: sequential (numpy last-writer-wins) override, one thread per batch.
__global__ void k_match_b(const ull* __restrict__ best_prior,
                          float* __restrict__ bto, int* __restrict__ bti) {
    const int b = threadIdx.x;
    if (b >= BB) return;
    for (int o = 0; o < OO; o++) {
        const unsigned p = 0xFFFFFFFFu - (unsigned)(best_prior[b * OO + o] & 0xFFFFFFFFull);
        bto[(size_t)b * PP + p] = 2.0f;
        bti[(size_t)b * PP + p] = o;
    }
}

// ---------------------------------------------------------------------------
// K2: tile of 64 rows per block, staged through LDS with coalesced float4
// loads. LSE by 4 threads/row; epilogue by 64 threads (exactly wave 0).
// Positive-set contributions are wave-reduced (__shfl_down/__ballot) and
// lane 0 issues <=5 atomics per block into STRIPED accumulators:
//   accS[blockIdx&63][0..2] = {loss_l, pos_ce_obj, pos_ce_c}  (128B stripes)
//   num_posS[blockIdx&7][b]                                   (128B stripes)
// This replaces the per-positive same-cacheline atomics that serialized v0.
// ---------------------------------------------------------------------------
__global__ __launch_bounds__(256) void k_ce(
        const float* __restrict__ conf, const float* __restrict__ obj,
        const float* __restrict__ loc, const float* __restrict__ priors,
        const float* __restrict__ truths, const int* __restrict__ labels,
        const float* __restrict__ bto, const int* __restrict__ bti,
        float* __restrict__ mining_obj, float* __restrict__ mining_c,
        int* __restrict__ num_posS /* [8][BB] */,
        float* __restrict__ accS  /* [64][32] */) {
    const int tid = threadIdx.x;
    const int row0 = blockIdx.x * 64;            // BP == 64 * gridDim.x exactly
    __shared__ float sconf[64 * CC];             // 20736 B
    __shared__ float slse[64];

    const float4* src = (const float4*)(conf + (size_t)row0 * CC);
    float4* dst = (float4*)sconf;
    for (int i = tid; i < (64 * CC) / 4; i += 256) dst[i] = src[i];
    __syncthreads();

    const int r = tid >> 2;
    const int part = tid & 3;
    const float* rowp = sconf + r * CC;
    const int c0 = part * 20;
    const int c1 = (part == 3) ? CC : c0 + 20;   // 20,20,20,21
    float m = -INFINITY;
    for (int c = c0; c < c1; c++) m = fmaxf(m, rowp[c]);
    m = fmaxf(m, __shfl_xor(m, 1));
    m = fmaxf(m, __shfl_xor(m, 2));
    float s = 0.0f;
    for (int c = c0; c < c1; c++) s += __expf(rowp[c] - m);
    s += __shfl_xor(s, 1);
    s += __shfl_xor(s, 2);
    if (part == 0) slse[r] = m + __logf(s);
    __syncthreads();

    if (tid < 64) {                              // exactly wave 0
        const int row = row0 + tid;
        const int b = row / PP;
        const int p = row - b * PP;
        const float ov = bto[row];
        const int ti = bti[row];
        const int lbl = labels[b * OO + ti];
        const int tgt = (ov < 0.5f) ? 0 : lbl;
        const float ce_c = slse[tid] - sconf[tid * CC + tgt];

        const float2 o2 = ((const float2*)obj)[row];
        const float mo = fmaxf(o2.x, o2.y);
        const float lse_o = mo + __logf(__expf(o2.x - mo) + __expf(o2.y - mo));
        const bool pos = tgt > 0;
        const float ce_o = lse_o - (pos ? o2.y : o2.x);

        mining_c[row]   = pos ? 0.0f : ce_c;
        mining_obj[row] = pos ? 0.0f : ce_o;

        float my_l = 0.0f, my_co = 0.0f, my_cc = 0.0f;
        if (pos) {
            my_co = ce_o;
            my_cc = ce_c;
            const float4 pr = ((const float4*)priors)[p];
            const float4 t  = ((const float4*)truths)[b * OO + ti];
            const float gcx = ((t.x + t.z) * 0.5f - pr.x) / (0.1f * pr.z);
            const float gcy = ((t.y + t.w) * 0.5f - pr.y) / (0.1f * pr.w);
            const float gw = logf((t.z - t.x) / pr.z) / 0.2f;
            const float gh = logf((t.w - t.y) / pr.w) / 0.2f;
            const float4 ld = ((const float4*)loc)[row];
            my_l = sl1(ld.x - gcx) + sl1(ld.y - gcy) +
                   sl1(ld.z - gw) + sl1(ld.w - gh);
        }

        // --- wave-level reduction: counts via ballot, sums via shfl tree ---
        const int b0 = row0 / PP;                // batch of first row in block
        const ull mpos = __ballot(pos);
        const ull mb1  = __ballot(b != b0);      // rows spilling into batch b0+1
#pragma unroll
        for (int d = 32; d; d >>= 1) {
            my_l  += __shfl_down(my_l,  d);
            my_co += __shfl_down(my_co, d);
            my_cc += __shfl_down(my_cc, d);
        }
        if (tid == 0 && mpos) {
            const int cnt0 = __popcll(mpos & ~mb1);
            const int cnt1 = __popcll(mpos &  mb1);
            int* nps = num_posS + (blockIdx.x & 7) * BB;
            if (cnt0) atomicAdd(&nps[b0], cnt0);
            if (cnt1) atomicAdd(&nps[b0 + 1], cnt1);
            float* slot = accS + (size_t)(blockIdx.x & 63) * 32;
            atomicAdd(slot + 0, my_l);
            atomicAdd(slot + 1, my_co);
            atomicAdd(slot + 2, my_cc);
        }
    }
}

// ---------------------------------------------------------------------------
// K3: top-k sum via 4-pass byte radix-select. 64 blocks: {obj,c} x 32 batches.
// ---------------------------------------------------------------------------
__global__ __launch_bounds__(256) void k_select(
        const float* __restrict__ mining /* [2][B][P] */,
        const int* __restrict__ num_posS /* [8][BB] */,
        float* __restrict__ acc,
        int* __restrict__ n1_acc) {
    const int arr = blockIdx.x >> 5;  // 0 = obj, 1 = c
    const int b = blockIdx.x & 31;
    const float* x = mining + ((size_t)arr * BB + b) * PP;
    int np = 0;
#pragma unroll
    for (int s = 0; s < 8; s++) np += num_posS[s * BB + b];
    long long k64 = 3LL * np;
    const int k = (int)(k64 < (long long)(PP - 1) ? k64 : (long long)(PP - 1));
    if (threadIdx.x == 0 && arr == 0) atomicAdd(n1_acc, k);
    if (k <= 0) return;

    __shared__ unsigned hist[256];
    __shared__ unsigned s_prefix;
    __shared__ int s_krem;
    if (threadIdx.x == 0) { s_prefix = 0u; s_krem = k; }
    __syncthreads();

    for (int shift = 24; shift >= 0; shift -= 8) {
        hist[threadIdx.x] = 0u;
        __syncthreads();
        const unsigned prefix = s_prefix;
        const unsigned pmask = (shift == 24) ? 0u : (0xFFFFFFFFu << (shift + 8));
        for (int i = threadIdx.x; i < PP; i += 256) {
            const unsigned u = __float_as_uint(x[i]);
            if ((u & pmask) == prefix)
                atomicAdd(&hist[(u >> shift) & 255u], 1u);
        }
        __syncthreads();
        if (threadIdx.x == 0) {
            const int krem = s_krem;
            unsigned cum = 0;
            int sel = 0;
            for (int byte = 255; byte >= 0; byte--) {
                const unsigned h = hist[byte];
                if (cum + h >= (unsigned)krem) { sel = byte; break; }
                cum += h;
            }
            s_krem = krem - (int)cum;
            s_prefix = prefix | ((unsigned)sel << shift);
        }
        __syncthreads();
    }

    const unsigned t = s_prefix;
    float lsum = 0.0f;
    unsigned lcnt = 0;
    for (int i = threadIdx.x; i < PP; i += 256) {
        const float v = x[i];
        if (__float_as_uint(v) > t) { lsum += v; lcnt++; }
    }
    __shared__ float sred[256];
    __shared__ unsigned cred[256];
    sred[threadIdx.x] = lsum;
    cred[threadIdx.x] = lcnt;
    __syncthreads();
    for (int st = 128; st; st >>= 1) {
        if (threadIdx.x < st) {
            sred[threadIdx.x] += sred[threadIdx.x + st];
            cred[threadIdx.x] += cred[threadIdx.x + st];
        }
        __syncthreads();
    }
    if (threadIdx.x == 0) {
        const float tsum = sred[0] + (float)(k - (int)cred[0]) * __uint_as_float(t);
        atomicAdd(&acc[3 + arr], tsum);
    }
}

// K4: final scalars. One wave; sums the striped accumulators.
__global__ void k_final(const float* __restrict__ acc,
                        const float* __restrict__ accS /* [64][32] */,
                        const int* __restrict__ num_posS /* [8][BB] = 256 ints */,
                        const int* __restrict__ n1_acc,
                        float* __restrict__ out) {
    const int t = threadIdx.x;   // 64 threads
    float sl = accS[t * 32 + 0];
    float so = accS[t * 32 + 1];
    float sc = accS[t * 32 + 2];
    int np = 0;
#pragma unroll
    for (int i = 0; i < 4; i++) np += num_posS[t + i * 64];
#pragma unroll
    for (int d = 32; d; d >>= 1) {
        sl += __shfl_down(sl, d);
        so += __shfl_down(so, d);
        sc += __shfl_down(sc, d);
        np += __shfl_down(np, d);
    }
    if (t == 0) {
        const float fN = (float)(np > 1 ? np : 1);
        const int n1 = *n1_acc;
        const float fN1 = (float)(n1 > 1 ? n1 : 1);
        out[0] = sl / fN;
        out[1] = (sc + acc[4]) / fN;
        out[2] = 0.4f * (so + acc[3]) / fN1;
    }
}

extern "C" void kernel_launch(void* const* d_in, const int* in_sizes, int n_in,
                              void* d_out, int out_size, void* d_ws, size_t ws_size,
                              hipStream_t stream) {
    const float* loc_data  = (const float*)d_in[0];
    const float* conf_data = (const float*)d_in[1];
    const float* obj_data  = (const float*)d_in[2];
    const float* priors    = (const float*)d_in[3];
    const float* truths    = (const float*)d_in[4];
    const int*   labels    = (const int*)d_in[5];
    float* out = (float*)d_out;

    // Workspace layout (float offsets from ws_f):
    // [0, BP)               bto
    // [BP, 2BP)             bti (int)
    // [2BP, 4BP)            mining: [0]=obj, [1]=c
    // [4BP, 4BP+1024)       best_prior: 512 ull
    // [4BP+1024, +1280)     num_posS: 8 stripes x 32 ints (128B apart)
    // [4BP+1280, +1288)     acc: 8 floats ([3]=neg_obj, [4]=neg_c)
    // [4BP+1288]            n1_acc (int)
    // [4BP+2048, +4096)     accS: 64 stripes x 32 floats (128B apart)
    float* ws_f = (float*)d_ws;
    float* bto = ws_f;
    int*   bti = (int*)(ws_f + BP);
    float* mining = ws_f + 2 * (size_t)BP;
    ull*   best_prior = (ull*)(ws_f + 4 * (size_t)BP);
    int*   num_posS = (int*)(ws_f + 4 * (size_t)BP + 1024);
    float* acc = ws_f + 4 * (size_t)BP + 1280;
    int*   n1_acc = (int*)(ws_f + 4 * (size_t)BP + 1288);
    float* accS = ws_f + 4 * (size_t)BP + 2048;

    // zero best_prior + num_posS + acc + n1 + accS in one shot (16 KiB)
    hipMemsetAsync((void*)best_prior, 0, 16384, stream);

    dim3 mg((PP + CHUNK - 1) / CHUNK, BB);
    k_match_a<<<mg, 256, 0, stream>>>(priors, truths, bto, bti, best_prior);
    k_match_b<<<1, 32, 0, stream>>>(best_prior, bto, bti);

    k_ce<<<BP / 64, 256, 0, stream>>>(conf_data, obj_data, loc_data, priors,
                                      truths, labels, bto, bti,
                                      mining /*obj*/, mining + BP /*c*/,
                                      num_posS, accS);

    k_select<<<64, 256, 0, stream>>>(mining, num_posS, acc, n1_acc);

    k_final<<<1, 64, 0, stream>>>(acc, accS, num_posS, n1_acc, out);
}

// Round 2
// 459.858 us; speedup vs baseline: 1.7907x; 1.2254x over previous
//
#include <hip/hip_runtime.h>
#include <hip/hip_bf16.h>
#include <math.h>

// Problem constants (fixed by the reference setup_inputs)
#define BB 32
#define PP 24564
#define OO 16
#define CC 81
#define BP (BB * PP)
#define CHUNK 1024   // priors per k_match_a block; ceil(PP/CHUNK)=24 chunks

typedef unsigned long long ull;

__device__ __forceinline__ float sl1(float x) {
    float ax = fabsf(x);
    return ax < 1.0f ? 0.5f * ax * ax : ax - 0.5f;
}

// ---------------------------------------------------------------------------
// K1a: matching, parallel over (chunk, batch). Computes per-prior best-truth
// (bto/bti) and per-truth best-prior via packed-key max:
//   key = (iou_bits << 32) | (0xFFFFFFFF - p)   -> max iou, tie: smallest p
// v2: per-truth best-prior reduced via wave shfl_xor butterfly (was: 4096
// same-address LDS 64-bit atomics per block, lane-serialized by HW).
// ---------------------------------------------------------------------------
__global__ __launch_bounds__(256) void k_match_a(
        const float* __restrict__ priors, const float* __restrict__ truths,
        float* __restrict__ bto, int* __restrict__ bti,
        ull* __restrict__ best_prior /* [BB][OO], pre-zeroed */) {
    const int b = blockIdx.y;
    const int p0 = blockIdx.x * CHUNK;
    const int tid = threadIdx.x;
    __shared__ float tr[OO][4];
    __shared__ float tarea[OO];
    __shared__ ull red[4][OO];
    if (tid < OO * 4) ((float*)tr)[tid] = truths[b * OO * 4 + tid];
    __syncthreads();
    if (tid < OO) tarea[tid] = (tr[tid][2] - tr[tid][0]) * (tr[tid][3] - tr[tid][1]);
    __syncthreads();

    float bpv[OO];
    int bpi[OO];
#pragma unroll
    for (int o = 0; o < OO; o++) { bpv[o] = -1.0f; bpi[o] = -1; }

    const int pend = (p0 + CHUNK < PP) ? p0 + CHUNK : PP;
    for (int p = p0 + tid; p < pend; p += 256) {
        const float4 pr = ((const float4*)priors)[p];
        const float x1 = pr.x - pr.z * 0.5f, y1 = pr.y - pr.w * 0.5f;
        const float x2 = pr.x + pr.z * 0.5f, y2 = pr.y + pr.w * 0.5f;
        const float parea = (x2 - x1) * (y2 - y1);
        float best = -1.0f;
        int bidx = 0;
#pragma unroll
        for (int o = 0; o < OO; o++) {
            const float lx = fmaxf(tr[o][0], x1), ly = fmaxf(tr[o][1], y1);
            const float rx = fminf(tr[o][2], x2), ry = fminf(tr[o][3], y2);
            const float iw = fmaxf(rx - lx, 0.0f), ih = fmaxf(ry - ly, 0.0f);
            const float inter = iw * ih;
            const float iou = inter / (tarea[o] + parea - inter);
            if (iou > best) { best = iou; bidx = o; }          // first-max over o
            if (iou > bpv[o]) { bpv[o] = iou; bpi[o] = p; }    // p ascending per thread
        }
        bto[(size_t)b * PP + p] = best;
        bti[(size_t)b * PP + p] = bidx;
    }

    // wave-level butterfly max-reduce of the packed key, per truth o
    const int wave = tid >> 6;
    const int lane = tid & 63;
#pragma unroll
    for (int o = 0; o < OO; o++) {
        ull key = (bpi[o] >= 0)
            ? (((ull)__float_as_uint(bpv[o]) << 32) |
               (ull)(0xFFFFFFFFu - (unsigned)bpi[o]))
            : 0ull;
#pragma unroll
        for (int d = 32; d; d >>= 1) {
            const ull other = __shfl_xor(key, d);
            key = (other > key) ? other : key;
        }
        if (lane == 0) red[wave][o] = key;
    }
    __syncthreads();
    if (tid < OO) {
        const ull k0 = red[0][tid], k1 = red[1][tid];
        const ull k2 = red[2][tid], k3 = red[3][tid];
        ull m = k0 > k1 ? k0 : k1;
        const ull m2 = k2 > k3 ? k2 : k3;
        m = m > m2 ? m : m2;
        if (m != 0ull) atomicMax(&best_prior[b * OO + tid], m);
    }
}

// K1b: sequential (numpy last-writer-wins) override, one thread per batch.
__global__ void k_match_b(const ull* __restrict__ best_prior,
                          float* __restrict__ bto, int* __restrict__ bti) {
    const int b = threadIdx.x;
    if (b >= BB) return;
    for (int o = 0; o < OO; o++) {
        const unsigned p = 0xFFFFFFFFu - (unsigned)(best_prior[b * OO + o] & 0xFFFFFFFFull);
        bto[(size_t)b * PP + p] = 2.0f;
        bti[(size_t)b * PP + p] = o;
    }
}

// ---------------------------------------------------------------------------
// K2: tile of 64 rows per block, staged through LDS with coalesced float4
// loads. LSE by 4 threads/row; epilogue by 64 threads (exactly wave 0).
// Positive-set contributions are wave-reduced (__shfl_down/__ballot) and
// lane 0 issues <=5 atomics per block into STRIPED accumulators.
// ---------------------------------------------------------------------------
__global__ __launch_bounds__(256) void k_ce(
        const float* __restrict__ conf, const float* __restrict__ obj,
        const float* __restrict__ loc, const float* __restrict__ priors,
        const float* __restrict__ truths, const int* __restrict__ labels,
        const float* __restrict__ bto, const int* __restrict__ bti,
        float* __restrict__ mining_obj, float* __restrict__ mining_c,
        int* __restrict__ num_posS /* [8][BB] */,
        float* __restrict__ accS  /* [64][32] */) {
    const int tid = threadIdx.x;
    const int row0 = blockIdx.x * 64;            // BP == 64 * gridDim.x exactly
    __shared__ float sconf[64 * CC];             // 20736 B
    __shared__ float slse[64];

    const float4* src = (const float4*)(conf + (size_t)row0 * CC);
    float4* dst = (float4*)sconf;
    for (int i = tid; i < (64 * CC) / 4; i += 256) dst[i] = src[i];
    __syncthreads();

    const int r = tid >> 2;
    const int part = tid & 3;
    const float* rowp = sconf + r * CC;
    const int c0 = part * 20;
    const int c1 = (part == 3) ? CC : c0 + 20;   // 20,20,20,21
    float m = -INFINITY;
    for (int c = c0; c < c1; c++) m = fmaxf(m, rowp[c]);
    m = fmaxf(m, __shfl_xor(m, 1));
    m = fmaxf(m, __shfl_xor(m, 2));
    float s = 0.0f;
    for (int c = c0; c < c1; c++) s += __expf(rowp[c] - m);
    s += __shfl_xor(s, 1);
    s += __shfl_xor(s, 2);
    if (part == 0) slse[r] = m + __logf(s);
    __syncthreads();

    if (tid < 64) {                              // exactly wave 0
        const int row = row0 + tid;
        const int b = row / PP;
        const int p = row - b * PP;
        const float ov = bto[row];
        const int ti = bti[row];
        const int lbl = labels[b * OO + ti];
        const int tgt = (ov < 0.5f) ? 0 : lbl;
        const float ce_c = slse[tid] - sconf[tid * CC + tgt];

        const float2 o2 = ((const float2*)obj)[row];
        const float mo = fmaxf(o2.x, o2.y);
        const float lse_o = mo + __logf(__expf(o2.x - mo) + __expf(o2.y - mo));
        const bool pos = tgt > 0;
        const float ce_o = lse_o - (pos ? o2.y : o2.x);

        mining_c[row]   = pos ? 0.0f : ce_c;
        mining_obj[row] = pos ? 0.0f : ce_o;

        float my_l = 0.0f, my_co = 0.0f, my_cc = 0.0f;
        if (pos) {
            my_co = ce_o;
            my_cc = ce_c;
            const float4 pr = ((const float4*)priors)[p];
            const float4 t  = ((const float4*)truths)[b * OO + ti];
            const float gcx = ((t.x + t.z) * 0.5f - pr.x) / (0.1f * pr.z);
            const float gcy = ((t.y + t.w) * 0.5f - pr.y) / (0.1f * pr.w);
            const float gw = logf((t.z - t.x) / pr.z) / 0.2f;
            const float gh = logf((t.w - t.y) / pr.w) / 0.2f;
            const float4 ld = ((const float4*)loc)[row];
            my_l = sl1(ld.x - gcx) + sl1(ld.y - gcy) +
                   sl1(ld.z - gw) + sl1(ld.w - gh);
        }

        // --- wave-level reduction: counts via ballot, sums via shfl tree ---
        const int b0 = row0 / PP;                // batch of first row in block
        const ull mpos = __ballot(pos);
        const ull mb1  = __ballot(b != b0);      // rows spilling into batch b0+1
#pragma unroll
        for (int d = 32; d; d >>= 1) {
            my_l  += __shfl_down(my_l,  d);
            my_co += __shfl_down(my_co, d);
            my_cc += __shfl_down(my_cc, d);
        }
        if (tid == 0 && mpos) {
            const int cnt0 = __popcll(mpos & ~mb1);
            const int cnt1 = __popcll(mpos &  mb1);
            int* nps = num_posS + (blockIdx.x & 7) * BB;
            if (cnt0) atomicAdd(&nps[b0], cnt0);
            if (cnt1) atomicAdd(&nps[b0 + 1], cnt1);
            float* slot = accS + (size_t)(blockIdx.x & 63) * 32;
            atomicAdd(slot + 0, my_l);
            atomicAdd(slot + 1, my_co);
            atomicAdd(slot + 2, my_cc);
        }
    }
}

// ---------------------------------------------------------------------------
// K3: top-k sum via 4-pass byte radix-select. 64 blocks: {obj,c} x 32 batches.
// v2: 1024 threads/block (was 256): 24 strided iters/pass instead of 96,
// 16 waves of latency hiding per CU.
// ---------------------------------------------------------------------------
__global__ __launch_bounds__(1024) void k_select(
        const float* __restrict__ mining /* [2][B][P] */,
        const int* __restrict__ num_posS /* [8][BB] */,
        float* __restrict__ acc,
        int* __restrict__ n1_acc) {
    const int arr = blockIdx.x >> 5;  // 0 = obj, 1 = c
    const int b = blockIdx.x & 31;
    const int tid = threadIdx.x;
    const float* x = mining + ((size_t)arr * BB + b) * PP;
    int np = 0;
#pragma unroll
    for (int s = 0; s < 8; s++) np += num_posS[s * BB + b];
    long long k64 = 3LL * np;
    const int k = (int)(k64 < (long long)(PP - 1) ? k64 : (long long)(PP - 1));
    if (tid == 0 && arr == 0) atomicAdd(n1_acc, k);
    if (k <= 0) return;

    __shared__ unsigned hist[256];
    __shared__ unsigned s_prefix;
    __shared__ int s_krem;
    __shared__ float wsum[16];
    __shared__ unsigned wcnt[16];
    if (tid == 0) { s_prefix = 0u; s_krem = k; }

    for (int shift = 24; shift >= 0; shift -= 8) {
        __syncthreads();                       // prefix/krem ready; hist free
        if (tid < 256) hist[tid] = 0u;
        const unsigned prefix = s_prefix;
        const unsigned pmask = (shift == 24) ? 0u : (0xFFFFFFFFu << (shift + 8));
        __syncthreads();                       // hist zeroed
        for (int i = tid; i < PP; i += 1024) {
            const unsigned u = __float_as_uint(x[i]);
            if ((u & pmask) == prefix)
                atomicAdd(&hist[(u >> shift) & 255u], 1u);
        }
        __syncthreads();
        if (tid == 0) {
            const int krem = s_krem;
            unsigned cum = 0;
            int sel = 0;
            for (int byte = 255; byte >= 0; byte--) {
                const unsigned h = hist[byte];
                if (cum + h >= (unsigned)krem) { sel = byte; break; }
                cum += h;
            }
            s_krem = krem - (int)cum;
            s_prefix = prefix | ((unsigned)sel << shift);
        }
    }
    __syncthreads();

    const unsigned t = s_prefix;
    float lsum = 0.0f;
    unsigned lcnt = 0;
    for (int i = tid; i < PP; i += 1024) {
        const float v = x[i];
        if (__float_as_uint(v) > t) { lsum += v; lcnt++; }
    }
#pragma unroll
    for (int d = 32; d; d >>= 1) {
        lsum += __shfl_down(lsum, d);
        lcnt += __shfl_down(lcnt, d);
    }
    const int wave = tid >> 6;
    if ((tid & 63) == 0) { wsum[wave] = lsum; wcnt[wave] = lcnt; }
    __syncthreads();
    if (tid == 0) {
        float ts = 0.0f;
        unsigned tc = 0;
#pragma unroll
        for (int w = 0; w < 16; w++) { ts += wsum[w]; tc += wcnt[w]; }
        const float tsum = ts + (float)(k - (int)tc) * __uint_as_float(t);
        atomicAdd(&acc[3 + arr], tsum);
    }
}

// K4: final scalars. One wave; sums the striped accumulators.
__global__ void k_final(const float* __restrict__ acc,
                        const float* __restrict__ accS /* [64][32] */,
                        const int* __restrict__ num_posS /* [8][BB] = 256 ints */,
                        const int* __restrict__ n1_acc,
                        float* __restrict__ out) {
    const int t = threadIdx.x;   // 64 threads
    float sl = accS[t * 32 + 0];
    float so = accS[t * 32 + 1];
    float sc = accS[t * 32 + 2];
    int np = 0;
#pragma unroll
    for (int i = 0; i < 4; i++) np += num_posS[t + i * 64];
#pragma unroll
    for (int d = 32; d; d >>= 1) {
        sl += __shfl_down(sl, d);
        so += __shfl_down(so, d);
        sc += __shfl_down(sc, d);
        np += __shfl_down(np, d);
    }
    if (t == 0) {
        const float fN = (float)(np > 1 ? np : 1);
        const int n1 = *n1_acc;
        const float fN1 = (float)(n1 > 1 ? n1 : 1);
        out[0] = sl / fN;
        out[1] = (sc + acc[4]) / fN;
        out[2] = 0.4f * (so + acc[3]) / fN1;
    }
}

extern "C" void kernel_launch(void* const* d_in, const int* in_sizes, int n_in,
                              void* d_out, int out_size, void* d_ws, size_t ws_size,
                              hipStream_t stream) {
    const float* loc_data  = (const float*)d_in[0];
    const float* conf_data = (const float*)d_in[1];
    const float* obj_data  = (const float*)d_in[2];
    const float* priors    = (const float*)d_in[3];
    const float* truths    = (const float*)d_in[4];
    const int*   labels    = (const int*)d_in[5];
    float* out = (float*)d_out;

    // Workspace layout (float offsets from ws_f):
    // [0, BP)               bto
    // [BP, 2BP)             bti (int)
    // [2BP, 4BP)            mining: [0]=obj, [1]=c
    // [4BP, 4BP+1024)       best_prior: 512 ull
    // [4BP+1024, +1280)     num_posS: 8 stripes x 32 ints (128B apart)
    // [4BP+1280, +1288)     acc: 8 floats ([3]=neg_obj, [4]=neg_c)
    // [4BP+1288]            n1_acc (int)
    // [4BP+2048, +4096)     accS: 64 stripes x 32 floats (128B apart)
    float* ws_f = (float*)d_ws;
    float* bto = ws_f;
    int*   bti = (int*)(ws_f + BP);
    float* mining = ws_f + 2 * (size_t)BP;
    ull*   best_prior = (ull*)(ws_f + 4 * (size_t)BP);
    int*   num_posS = (int*)(ws_f + 4 * (size_t)BP + 1024);
    float* acc = ws_f + 4 * (size_t)BP + 1280;
    int*   n1_acc = (int*)(ws_f + 4 * (size_t)BP + 1288);
    float* accS = ws_f + 4 * (size_t)BP + 2048;

    // zero best_prior + num_posS + acc + n1 + accS in one shot (16 KiB)
    hipMemsetAsync((void*)best_prior, 0, 16384, stream);

    dim3 mg((PP + CHUNK - 1) / CHUNK, BB);
    k_match_a<<<mg, 256, 0, stream>>>(priors, truths, bto, bti, best_prior);
    k_match_b<<<1, 32, 0, stream>>>(best_prior, bto, bti);

    k_ce<<<BP / 64, 256, 0, stream>>>(conf_data, obj_data, loc_data, priors,
                                      truths, labels, bto, bti,
                                      mining /*obj*/, mining + BP /*c*/,
                                      num_posS, accS);

    k_select<<<64, 1024, 0, stream>>>(mining, num_posS, acc, n1_acc);

    k_final<<<1, 64, 0, stream>>>(acc, accS, num_posS, n1_acc, out);
}